// Round 15
// baseline (827.707 us; speedup 1.0000x reference)
//
#include <hip/hip_runtime.h>
#include <hip/hip_bf16.h>

typedef __attribute__((ext_vector_type(8))) __bf16 bf16x8;
typedef __attribute__((ext_vector_type(4))) __bf16 bf16x4;
typedef __attribute__((ext_vector_type(4))) float f32x4;

#define LOG2E 1.44269504088896340736f

__device__ inline f32x4 mfma16(bf16x8 a, bf16x8 b, f32x4 c) {
  return __builtin_amdgcn_mfma_f32_16x16x32_bf16(a, b, c, 0, 0, 0);
}

// row/w division for w in {32,48}, kg < 4096
__device__ inline int rowdiv(int kg, int w) {
  return (w == 32) ? (kg >> 5) : ((kg * 43691) >> 21);
}

// async global->LDS DMA, 16B per lane; lds addr must be wave-uniform base
__device__ __forceinline__ void dma16(const void* g, void* l) {
  __builtin_amdgcn_global_load_lds(
      (const __attribute__((address_space(1))) void*)g,
      (__attribute__((address_space(3))) void*)l, 16, 0, 0);
}

// ------------------------------------------------------------------
// Projection with bf16-pair (hi+lo) precision:
// X fp32 [B][64][16384] -> QT/KT bf16-pair [B][16384][hi64|lo64],
// Vh/Vl bf16 [B][64][16384] (ch-major). Q scaled by log2(e); bk dropped.
// ------------------------------------------------------------------
__global__ __launch_bounds__(256) void proj_kernel(
    const float* __restrict__ X, const float* __restrict__ Wq,
    const float* __restrict__ Wk, const float* __restrict__ Wv,
    const float* __restrict__ bq, const float* __restrict__ bv,
    __bf16* __restrict__ QT, __bf16* __restrict__ KT,
    __bf16* __restrict__ Vh, __bf16* __restrict__ Vl)
{
  const int b = blockIdx.y;
  const int pixbase = blockIdx.x * 256;
  const int t = threadIdx.x;
  __shared__ __align__(16) __bf16 xs[256 * 128]; // [pix][hi64|lo64], row-XOR-swizzled

  { // stage X tile split into hi/lo
    const float* xp = X + (size_t)b * 64 * 16384 + pixbase + t;
    #pragma unroll
    for (int c8 = 0; c8 < 8; ++c8) {
      bf16x8 vh, vl;
      #pragma unroll
      for (int i = 0; i < 8; ++i) {
        float x = xp[(size_t)(c8 * 8 + i) * 16384];
        __bf16 h = (__bf16)x;
        vh[i] = h;
        vl[i] = (__bf16)(x - (float)h);
      }
      int col = (c8 * 8) ^ ((t & 7) << 3);
      *(bf16x8*)&xs[t * 128 + col] = vh;
      *(bf16x8*)&xs[t * 128 + 64 + col] = vl;
    }
  }
  __syncthreads();

  const int wv = t >> 6, lane = t & 63, g = lane >> 4, lq = lane & 15;

  // X as B-fragments: B[k=ci][n=pix], hi and lo
  bf16x8 xf[4][2][2];
  #pragma unroll
  for (int nt = 0; nt < 4; ++nt)
    #pragma unroll
    for (int ks = 0; ks < 2; ++ks) {
      int pixl = wv * 64 + nt * 16 + lq;
      int col = (ks * 32 + g * 8) ^ ((pixl & 7) << 3);
      xf[nt][ks][0] = *(bf16x8*)&xs[pixl * 128 + col];
      xf[nt][ks][1] = *(bf16x8*)&xs[pixl * 128 + 64 + col];
    }

  #pragma unroll
  for (int mat = 0; mat < 3; ++mat) {
    const float* Wm = (mat == 0) ? Wq : (mat == 1) ? Wk : Wv;
    #pragma unroll
    for (int mt = 0; mt < 4; ++mt) {
      // W as A-fragments: A[m=co][k=ci], co = mt*16 + lq, hi/lo split
      bf16x8 wh[2], wl[2];
      #pragma unroll
      for (int ks = 0; ks < 2; ++ks) {
        const float* wp = Wm + (mt * 16 + lq) * 64 + ks * 32 + g * 8;
        f32x4 w0 = *(const f32x4*)wp;
        f32x4 w1 = *(const f32x4*)(wp + 4);
        bf16x8 fh, fl;
        #pragma unroll
        for (int r = 0; r < 4; ++r) {
          __bf16 h0 = (__bf16)w0[r]; fh[r] = h0; fl[r] = (__bf16)(w0[r] - (float)h0);
          __bf16 h1 = (__bf16)w1[r]; fh[4 + r] = h1; fl[4 + r] = (__bf16)(w1[r] - (float)h1);
        }
        wh[ks] = fh; wl[ks] = fl;
      }
      f32x4 binit = {0.f, 0.f, 0.f, 0.f};
      if (mat == 0) binit = *(const f32x4*)(bq + mt * 16 + g * 4);
      if (mat == 2) binit = *(const f32x4*)(bv + mt * 16 + g * 4);
      f32x4 acc[4];
      #pragma unroll
      for (int nt = 0; nt < 4; ++nt) acc[nt] = binit;
      #pragma unroll
      for (int nt = 0; nt < 4; ++nt)
        #pragma unroll
        for (int ks = 0; ks < 2; ++ks) {
          acc[nt] = mfma16(wh[ks], xf[nt][ks][0], acc[nt]);
          acc[nt] = mfma16(wh[ks], xf[nt][ks][1], acc[nt]);
          acc[nt] = mfma16(wl[ks], xf[nt][ks][0], acc[nt]);
        }
      // D layout: m = co = mt*16 + g*4 + r ; n = pix = nt*16 + lq
      #pragma unroll
      for (int nt = 0; nt < 4; ++nt) {
        int pix = pixbase + wv * 64 + nt * 16 + lq;
        if (mat == 2) {
          #pragma unroll
          for (int r = 0; r < 4; ++r) {
            float v = acc[nt][r];
            __bf16 h = (__bf16)v;
            size_t idx = ((size_t)b * 64 + mt * 16 + g * 4 + r) * 16384 + pix;
            Vh[idx] = h;
            Vl[idx] = (__bf16)(v - (float)h);
          }
        } else {
          bf16x4 oh, ol;
          #pragma unroll
          for (int r = 0; r < 4; ++r) {
            float v = (mat == 0) ? acc[nt][r] * LOG2E : acc[nt][r];
            __bf16 h = (__bf16)v;
            oh[r] = h;
            ol[r] = (__bf16)(v - (float)h);
          }
          __bf16* dst = (mat == 0 ? QT : KT) + ((size_t)b * 16384 + pix) * 128 + mt * 16 + g * 4;
          *(bf16x4*)dst = oh;
          *(bf16x4*)(dst + 64) = ol;
        }
      }
    }
  }
}

// ------------------------------------------------------------------
// Flash attention: DMA-staged K/V (double-buffered, zero VGPR cost) +
// anchored-max softmax + rotating 16-row lp.
// LDS = kbuf 32K + vbuf 32K + lp 16K = 80 KB -> 2 blocks/CU (exactly the
// grid cap), so one block's barrier drain overlaps the other's compute
// (R12's 1-block/CU version had no overlap partner and lost).
// Zero-VGPR loads fix R4/R14's real stall: qf(64)+s(64) regs left no room
// to keep 16 K-load results in flight -> serialized vmcnt waits.
// Anchored max (R14): per-row max computed once from chunk 0, then fixed.
// Rotating lp (R8-validated): P written+consumed inside the same qt iter.
// QK^T: 3-term bf16-pair. PV: 3-term bf16-pair.
// Block decode: xcd = batch (i&7), windows desc-Nk.
// ------------------------------------------------------------------
__global__ __launch_bounds__(256) void attn_kernel(
    const __bf16* __restrict__ QT, const __bf16* __restrict__ KT,
    const __bf16* __restrict__ Vh, const __bf16* __restrict__ Vl,
    const float* RES, float* OUT)
{
  const int i = blockIdx.x;
  const int b = i & 7;
  const int s_lin = i >> 3;
  const int wo = s_lin >> 2;
  const int qb = s_lin & 3;
  int win;
  {
    int w3 = (wo * 11) >> 5; // wo/3 for wo<9
    win = (wo < 9) ? (wo + w3) : ((wo < 12) ? (3 + ((wo - 9) << 2)) : wo);
  }
  const int wi = win >> 2, wj = win & 3;
  const int sx = wi * 32, sy = wj * 32;
  const int w = (128 - sy) < 48 ? (128 - sy) : 48;
  const int h = (128 - sx) < 48 ? (128 - sx) : 48;
  const int Nk = h * w, nch = Nk >> 6;
  const int t = threadIdx.x;
  const int wv = t >> 6, lane = t & 63, g = lane >> 4, lq = lane & 15;

  __shared__ __align__(16) __bf16 kbuf[2][64 * 128];  // [key][hi64|lo64] swizzled (32 KB)
  __shared__ __align__(16) __bf16 vbuf[2][128 * 64];  // [ch hi|lo][64key] swizzled (32 KB)
  __shared__ __align__(16) __bf16 lp[4][16 * 128];    // per-wave rotating P pair (16 KB)

  // Q fragments (B of S^T): B[k=ch][n=q]; wave owns rows r0,r0+1
  const int r0 = sx + qb * 8 + wv * 2;
  bf16x8 qf[4][2][2]; // [qt][ks][hi/lo]
  #pragma unroll
  for (int qt = 0; qt < 4; ++qt) {
    int qpix = (r0 + (qt >> 1)) * 128 + sy + (qt & 1) * 16 + lq;
    const __bf16* qp = QT + ((size_t)b * 16384 + qpix) * 128;
    qf[qt][0][0] = *(const bf16x8*)(qp + g * 8);
    qf[qt][1][0] = *(const bf16x8*)(qp + 32 + g * 8);
    qf[qt][0][1] = *(const bf16x8*)(qp + 64 + g * 8);
    qf[qt][1][1] = *(const bf16x8*)(qp + 96 + g * 8);
  }

  f32x4 O[4][4]; // O^T acc: m = ch = cht*16 + g*4 + r ; n = q
  #pragma unroll
  for (int qt = 0; qt < 4; ++qt)
    #pragma unroll
    for (int cht = 0; cht < 4; ++cht) O[qt][cht] = (f32x4){0.f, 0.f, 0.f, 0.f};
  float l[4] = {0.f, 0.f, 0.f, 0.f};
  float mfix[4];

  // ---- DMA stage of one 64-key chunk into buffer bu (R12-verified) ----
  auto stage = [&](int bu, int kbase) {
    #pragma unroll
    for (int j = 0; j < 4; ++j) { // K: 1024 16B slots, slot = j*256 + t
      int s = j * 256 + t;
      int key = s >> 4, u = s & 15;
      int su = u ^ (key & 7); // inverse swizzle on SOURCE
      int kg = kbase + key;
      int kr = rowdiv(kg, w), kc = kg - kr * w;
      const __bf16* gp = KT + ((size_t)b * 16384 + (sx + kr) * 128 + sy + kc) * 128 + su * 8;
      dma16(gp, &kbuf[bu][(size_t)(j * 256 + wv * 64) * 8]);
    }
    #pragma unroll
    for (int j = 0; j < 4; ++j) { // V: 1024 16B slots (128 ch-rows x 8 units)
      int s = j * 256 + t;
      int chn = s >> 3, cu = s & 7;
      int scu = cu ^ (chn & 7); // inverse swizzle on SOURCE
      int kg0 = kbase + scu * 8;
      int kr = rowdiv(kg0, w);
      int pix = (sx + kr) * 128 + sy + kg0 - kr * w;
      const __bf16* gp = (chn < 64)
          ? Vh + ((size_t)b * 64 + chn) * 16384 + pix
          : Vl + ((size_t)b * 64 + (chn - 64)) * 16384 + pix;
      dma16(gp, &vbuf[bu][(size_t)(j * 256 + wv * 64) * 8]);
    }
  };

  stage(0, 0);
  __syncthreads();

  for (int ch = 0; ch < nch; ++ch) {
    const int cur = ch & 1;
    if (ch + 1 < nch) stage(cur ^ 1, (ch + 1) * 64); // prefetch next chunk

    // ---- QK^T: S^T[key][q], K fragments from LDS ----
    f32x4 s[4][4]; // [qt][t4]
    #pragma unroll
    for (int qt = 0; qt < 4; ++qt)
      #pragma unroll
      for (int t4 = 0; t4 < 4; ++t4) s[qt][t4] = (f32x4){0.f, 0.f, 0.f, 0.f};
    #pragma unroll
    for (int t4 = 0; t4 < 4; ++t4) {
      const __bf16* kp = &kbuf[cur][(t4 * 16 + lq) * 128];
      int sw = (lq & 7) << 3;
      bf16x8 kh0 = *(const bf16x8*)&kp[(g * 8) ^ sw];
      bf16x8 kh1 = *(const bf16x8*)&kp[(32 + g * 8) ^ sw];
      bf16x8 kl0 = *(const bf16x8*)&kp[(64 + g * 8) ^ sw];
      bf16x8 kl1 = *(const bf16x8*)&kp[(96 + g * 8) ^ sw];
      __builtin_amdgcn_s_setprio(1);
      #pragma unroll
      for (int qt = 0; qt < 4; ++qt) {
        s[qt][t4] = mfma16(kh0, qf[qt][0][0], s[qt][t4]);
        s[qt][t4] = mfma16(kh0, qf[qt][0][1], s[qt][t4]);
        s[qt][t4] = mfma16(kl0, qf[qt][0][0], s[qt][t4]);
        s[qt][t4] = mfma16(kh1, qf[qt][1][0], s[qt][t4]);
        s[qt][t4] = mfma16(kh1, qf[qt][1][1], s[qt][t4]);
        s[qt][t4] = mfma16(kl1, qf[qt][1][0], s[qt][t4]);
      }
      __builtin_amdgcn_s_setprio(0);
    }

    // ---- anchor: per-row max from chunk 0 only (once per kernel) ----
    if (ch == 0) {
      #pragma unroll
      for (int qt = 0; qt < 4; ++qt) {
        float cm = -__builtin_inff();
        #pragma unroll
        for (int t4 = 0; t4 < 4; ++t4)
          #pragma unroll
          for (int r = 0; r < 4; ++r) cm = fmaxf(cm, s[qt][t4][r]);
        cm = fmaxf(cm, __shfl_xor(cm, 16));
        cm = fmaxf(cm, __shfl_xor(cm, 32));
        mfix[qt] = cm;
      }
    }

    // ---- per qt: anchored softmax -> rotating lp -> PV (V from LDS) ----
    #pragma unroll
    for (int qt = 0; qt < 4; ++qt) {
      float ps = 0.f;
      const int rowb = lq * 128; // rotating: no qt offset
      #pragma unroll
      for (int t4 = 0; t4 < 4; ++t4) {
        float p0 = exp2f(s[qt][t4][0] - mfix[qt]);
        float p1 = exp2f(s[qt][t4][1] - mfix[qt]);
        float p2 = exp2f(s[qt][t4][2] - mfix[qt]);
        float p3 = exp2f(s[qt][t4][3] - mfix[qt]);
        ps += (p0 + p1) + (p2 + p3);
        bf16x4 ph, pl;
        ph[0] = (__bf16)p0; pl[0] = (__bf16)(p0 - (float)ph[0]);
        ph[1] = (__bf16)p1; pl[1] = (__bf16)(p1 - (float)ph[1]);
        ph[2] = (__bf16)p2; pl[2] = (__bf16)(p2 - (float)ph[2]);
        ph[3] = (__bf16)p3; pl[3] = (__bf16)(p3 - (float)ph[3]);
        int col = (t4 * 16 + g * 4) ^ ((lq & 7) << 3);
        *(bf16x4*)&lp[wv][rowb + col] = ph;
        *(bf16x4*)&lp[wv][rowb + 64 + col] = pl;
      }
      ps += __shfl_xor(ps, 16);
      ps += __shfl_xor(ps, 32);
      l[qt] += ps;

      #pragma unroll
      for (int ks = 0; ks < 2; ++ks) {
        int vcol = (ks * 32 + g * 8) ^ ((lq & 7) << 3);
        bf16x8 vfh[4], vfl[4];
        #pragma unroll
        for (int cht = 0; cht < 4; ++cht) {
          vfh[cht] = *(const bf16x8*)&vbuf[cur][(cht * 16 + lq) * 64 + vcol];
          vfl[cht] = *(const bf16x8*)&vbuf[cur][(64 + cht * 16 + lq) * 64 + vcol];
        }
        bf16x8 pbh = *(bf16x8*)&lp[wv][rowb + vcol];
        bf16x8 pbl = *(bf16x8*)&lp[wv][rowb + 64 + vcol];
        __builtin_amdgcn_s_setprio(1);
        #pragma unroll
        for (int cht = 0; cht < 4; ++cht) {
          O[qt][cht] = mfma16(vfh[cht], pbh, O[qt][cht]);
          O[qt][cht] = mfma16(vfl[cht], pbh, O[qt][cht]);
          O[qt][cht] = mfma16(vfh[cht], pbl, O[qt][cht]);
        }
        __builtin_amdgcn_s_setprio(0);
      }
    }

    __syncthreads(); // all reads of cur done; next buffer's DMA drained
  }

  // epilogue: out = O/l + residual
  #pragma unroll
  for (int qt = 0; qt < 4; ++qt) {
    float inv = 1.0f / l[qt];
    int qpix = (r0 + (qt >> 1)) * 128 + sy + (qt & 1) * 16 + lq;
    #pragma unroll
    for (int cht = 0; cht < 4; ++cht)
      #pragma unroll
      for (int r = 0; r < 4; ++r) {
        int chn = cht * 16 + g * 4 + r;
        size_t idx = ((size_t)b * 64 + chn) * 16384 + qpix;
        OUT[idx] = O[qt][cht][r] * inv + RES[idx];
      }
  }
}

extern "C" void kernel_launch(void* const* d_in, const int* in_sizes, int n_in,
                              void* d_out, int out_size, void* d_ws, size_t ws_size,
                              hipStream_t stream) {
  const float* x   = (const float*)d_in[0];
  const float* Wq1 = (const float*)d_in[1];
  const float* Wk1 = (const float*)d_in[2];
  const float* Wv1 = (const float*)d_in[3];
  const float* Wq2 = (const float*)d_in[4];
  const float* Wk2 = (const float*)d_in[5];
  const float* Wv2 = (const float*)d_in[6];
  const float* bq1 = (const float*)d_in[7];
  /* bk1 = d_in[8], bk2 = d_in[11]: exactly cancel under softmax */
  const float* bv1 = (const float*)d_in[9];
  const float* bq2 = (const float*)d_in[10];
  const float* bv2 = (const float*)d_in[12];
  float* out = (float*)d_out;

  const size_t IMG = (size_t)8 * 16384;
  __bf16* QT = (__bf16*)d_ws;        // [8][16384][128]
  __bf16* KT = QT + IMG * 128;       // [8][16384][128]
  __bf16* Vh = KT + IMG * 128;       // [8][64][16384]
  __bf16* Vl = Vh + IMG * 64;        // [8][64][16384]

  dim3 pgrid(64, 8);
  // layer 1
  proj_kernel<<<pgrid, 256, 0, stream>>>(x, Wq1, Wk1, Wv1, bq1, bv1, QT, KT, Vh, Vl);
  attn_kernel<<<512, 256, 0, stream>>>(QT, KT, Vh, Vl, x, out);
  // layer 2 (reads layer-1 output from d_out; residual aliases output safely)
  proj_kernel<<<pgrid, 256, 0, stream>>>(out, Wq2, Wk2, Wv2, bq2, bv2, QT, KT, Vh, Vl);
  attn_kernel<<<512, 256, 0, stream>>>(QT, KT, Vh, Vl, out, out);
}

// Round 16
// 682.119 us; speedup vs baseline: 1.2134x; 1.2134x over previous
//
#include <hip/hip_runtime.h>
#include <hip/hip_bf16.h>

typedef __attribute__((ext_vector_type(8))) __bf16 bf16x8;
typedef __attribute__((ext_vector_type(4))) __bf16 bf16x4;
typedef __attribute__((ext_vector_type(8))) _Float16 f16x8;
typedef __attribute__((ext_vector_type(4))) _Float16 f16x4;
typedef __attribute__((ext_vector_type(4))) float f32x4;

#define LOG2E 1.44269504088896340736f

__device__ inline f32x4 mfma16(bf16x8 a, bf16x8 b, f32x4 c) {
  return __builtin_amdgcn_mfma_f32_16x16x32_bf16(a, b, c, 0, 0, 0);
}
__device__ inline f32x4 mfma16h(f16x8 a, f16x8 b, f32x4 c) {
  return __builtin_amdgcn_mfma_f32_16x16x32_f16(a, b, c, 0, 0, 0);
}

// row/w division for w in {32,48}, kg < 4096
__device__ inline int rowdiv(int kg, int w) {
  return (w == 32) ? (kg >> 5) : ((kg * 43691) >> 21);
}

// ------------------------------------------------------------------
// Projection: X fp32 [B][64][16384] -> QT/KT bf16-pair [B][16384][hi64|lo64]
// (QK path, unchanged), Vh/Vl f16-pair [B][64][16384] ch-major (PV path:
// f16's 10-bit mantissa lets PV run 2-term instead of 3-term).
// Q scaled by log2(e); bk dropped (softmax-invariant).
// ------------------------------------------------------------------
__global__ __launch_bounds__(256) void proj_kernel(
    const float* __restrict__ X, const float* __restrict__ Wq,
    const float* __restrict__ Wk, const float* __restrict__ Wv,
    const float* __restrict__ bq, const float* __restrict__ bv,
    __bf16* __restrict__ QT, __bf16* __restrict__ KT,
    _Float16* __restrict__ Vh, _Float16* __restrict__ Vl)
{
  const int b = blockIdx.y;
  const int pixbase = blockIdx.x * 256;
  const int t = threadIdx.x;
  __shared__ __align__(16) __bf16 xs[256 * 128]; // [pix][hi64|lo64], row-XOR-swizzled

  { // stage X tile split into hi/lo
    const float* xp = X + (size_t)b * 64 * 16384 + pixbase + t;
    #pragma unroll
    for (int c8 = 0; c8 < 8; ++c8) {
      bf16x8 vh, vl;
      #pragma unroll
      for (int i = 0; i < 8; ++i) {
        float x = xp[(size_t)(c8 * 8 + i) * 16384];
        __bf16 h = (__bf16)x;
        vh[i] = h;
        vl[i] = (__bf16)(x - (float)h);
      }
      int col = (c8 * 8) ^ ((t & 7) << 3);
      *(bf16x8*)&xs[t * 128 + col] = vh;
      *(bf16x8*)&xs[t * 128 + 64 + col] = vl;
    }
  }
  __syncthreads();

  const int wv = t >> 6, lane = t & 63, g = lane >> 4, lq = lane & 15;

  // X as B-fragments: B[k=ci][n=pix], hi and lo
  bf16x8 xf[4][2][2];
  #pragma unroll
  for (int nt = 0; nt < 4; ++nt)
    #pragma unroll
    for (int ks = 0; ks < 2; ++ks) {
      int pixl = wv * 64 + nt * 16 + lq;
      int col = (ks * 32 + g * 8) ^ ((pixl & 7) << 3);
      xf[nt][ks][0] = *(bf16x8*)&xs[pixl * 128 + col];
      xf[nt][ks][1] = *(bf16x8*)&xs[pixl * 128 + 64 + col];
    }

  #pragma unroll
  for (int mat = 0; mat < 3; ++mat) {
    const float* Wm = (mat == 0) ? Wq : (mat == 1) ? Wk : Wv;
    #pragma unroll
    for (int mt = 0; mt < 4; ++mt) {
      // W as A-fragments: A[m=co][k=ci], co = mt*16 + lq, hi/lo split
      bf16x8 wh[2], wl[2];
      #pragma unroll
      for (int ks = 0; ks < 2; ++ks) {
        const float* wp = Wm + (mt * 16 + lq) * 64 + ks * 32 + g * 8;
        f32x4 w0 = *(const f32x4*)wp;
        f32x4 w1 = *(const f32x4*)(wp + 4);
        bf16x8 fh, fl;
        #pragma unroll
        for (int r = 0; r < 4; ++r) {
          __bf16 h0 = (__bf16)w0[r]; fh[r] = h0; fl[r] = (__bf16)(w0[r] - (float)h0);
          __bf16 h1 = (__bf16)w1[r]; fh[4 + r] = h1; fl[4 + r] = (__bf16)(w1[r] - (float)h1);
        }
        wh[ks] = fh; wl[ks] = fl;
      }
      f32x4 binit = {0.f, 0.f, 0.f, 0.f};
      if (mat == 0) binit = *(const f32x4*)(bq + mt * 16 + g * 4);
      if (mat == 2) binit = *(const f32x4*)(bv + mt * 16 + g * 4);
      f32x4 acc[4];
      #pragma unroll
      for (int nt = 0; nt < 4; ++nt) acc[nt] = binit;
      #pragma unroll
      for (int nt = 0; nt < 4; ++nt)
        #pragma unroll
        for (int ks = 0; ks < 2; ++ks) {
          acc[nt] = mfma16(wh[ks], xf[nt][ks][0], acc[nt]);
          acc[nt] = mfma16(wh[ks], xf[nt][ks][1], acc[nt]);
          acc[nt] = mfma16(wl[ks], xf[nt][ks][0], acc[nt]);
        }
      // D layout: m = co = mt*16 + g*4 + r ; n = pix = nt*16 + lq
      #pragma unroll
      for (int nt = 0; nt < 4; ++nt) {
        int pix = pixbase + wv * 64 + nt * 16 + lq;
        if (mat == 2) {
          #pragma unroll
          for (int r = 0; r < 4; ++r) {
            float v = acc[nt][r];
            _Float16 h = (_Float16)v;
            size_t idx = ((size_t)b * 64 + mt * 16 + g * 4 + r) * 16384 + pix;
            Vh[idx] = h;
            Vl[idx] = (_Float16)(v - (float)h);
          }
        } else {
          bf16x4 oh, ol;
          #pragma unroll
          for (int r = 0; r < 4; ++r) {
            float v = (mat == 0) ? acc[nt][r] * LOG2E : acc[nt][r];
            __bf16 h = (__bf16)v;
            oh[r] = h;
            ol[r] = (__bf16)(v - (float)h);
          }
          __bf16* dst = (mat == 0 ? QT : KT) + ((size_t)b * 16384 + pix) * 128 + mt * 16 + g * 4;
          *(bf16x4*)dst = oh;
          *(bf16x4*)(dst + 64) = ol;
        }
      }
    }
  }
}

// ------------------------------------------------------------------
// Flash attention, barrier-free. 4 waves x 64 queries (2 rows) per block;
// K/V fragments direct from global, LDS only for the per-wave P plane.
// QK^T: 3-term bf16-pair (error-amplifying path, kept at max precision).
// PV: 2-term f16 (P single f16 + V f16-pair): f16's 10-bit mantissa gives
// 4x finer P than bf16, so the pl*vh term (which R3 showed bf16 needs) is
// droppable -> 64 instead of 96 PV MFMAs/chunk, no P-lo split (VALU -25%),
// lp halved to 32 KB. Defer-max THR=8 (R4-proven) bounds p <= 2^8 = 256,
// inside f16 range (anchored-max is NOT f16-safe: gap can reach 2^23).
// Block decode: xcd = batch (i&7), windows desc-Nk.
// ------------------------------------------------------------------
__global__ __launch_bounds__(256, 2) void attn_kernel(
    const __bf16* __restrict__ QT, const __bf16* __restrict__ KT,
    const _Float16* __restrict__ Vh, const _Float16* __restrict__ Vl,
    const float* RES, float* OUT)
{
  const int i = blockIdx.x;
  const int b = i & 7;
  const int s_lin = i >> 3;
  const int wo = s_lin >> 2;
  const int qb = s_lin & 3;
  int win;
  {
    int w3 = (wo * 11) >> 5; // wo/3 for wo<9
    win = (wo < 9) ? (wo + w3) : ((wo < 12) ? (3 + ((wo - 9) << 2)) : wo);
  }
  const int wi = win >> 2, wj = win & 3;
  const int sx = wi * 32, sy = wj * 32;
  const int w = (128 - sy) < 48 ? (128 - sy) : 48;
  const int h = (128 - sx) < 48 ? (128 - sx) : 48;
  const int Nk = h * w, nch = Nk >> 6;
  const int t = threadIdx.x;
  const int wv = t >> 6, lane = t & 63, g = lane >> 4, lq = lane & 15;

  __shared__ __align__(16) _Float16 lp[4][64 * 64]; // per-wave P (f16, 32 KB)

  // Q fragments (B of S^T): B[k=ch][n=q]; wave owns rows r0,r0+1
  const int r0 = sx + qb * 8 + wv * 2;
  bf16x8 qf[4][2][2]; // [qt][ks][hi/lo]
  #pragma unroll
  for (int qt = 0; qt < 4; ++qt) {
    int qpix = (r0 + (qt >> 1)) * 128 + sy + (qt & 1) * 16 + lq;
    const __bf16* qp = QT + ((size_t)b * 16384 + qpix) * 128;
    qf[qt][0][0] = *(const bf16x8*)(qp + g * 8);
    qf[qt][1][0] = *(const bf16x8*)(qp + 32 + g * 8);
    qf[qt][0][1] = *(const bf16x8*)(qp + 64 + g * 8);
    qf[qt][1][1] = *(const bf16x8*)(qp + 96 + g * 8);
  }

  f32x4 O[4][4]; // O^T acc: m = ch = cht*16 + g*4 + r ; n = q
  #pragma unroll
  for (int qt = 0; qt < 4; ++qt)
    #pragma unroll
    for (int cht = 0; cht < 4; ++cht) O[qt][cht] = (f32x4){0.f, 0.f, 0.f, 0.f};
  float m[4] = {-__builtin_inff(), -__builtin_inff(), -__builtin_inff(), -__builtin_inff()};
  float l[4] = {0.f, 0.f, 0.f, 0.f};

  for (int ch = 0; ch < nch; ++ch) {
    const int kbase = ch * 64;

    // ---- QK^T: S^T[key][q], K fragments direct from global ----
    f32x4 s[4][4]; // [qt][t4]
    #pragma unroll
    for (int qt = 0; qt < 4; ++qt)
      #pragma unroll
      for (int t4 = 0; t4 < 4; ++t4) s[qt][t4] = (f32x4){0.f, 0.f, 0.f, 0.f};
    #pragma unroll
    for (int t4 = 0; t4 < 4; ++t4) {
      int kg = kbase + t4 * 16 + lq;
      int kr = rowdiv(kg, w), kc = kg - kr * w;
      const __bf16* kp = KT + ((size_t)b * 16384 + (sx + kr) * 128 + sy + kc) * 128 + g * 8;
      bf16x8 kh0 = *(const bf16x8*)(kp);
      bf16x8 kh1 = *(const bf16x8*)(kp + 32);
      bf16x8 kl0 = *(const bf16x8*)(kp + 64);
      bf16x8 kl1 = *(const bf16x8*)(kp + 96);
      __builtin_amdgcn_s_setprio(1);
      #pragma unroll
      for (int qt = 0; qt < 4; ++qt) {
        s[qt][t4] = mfma16(kh0, qf[qt][0][0], s[qt][t4]);
        s[qt][t4] = mfma16(kh0, qf[qt][0][1], s[qt][t4]);
        s[qt][t4] = mfma16(kl0, qf[qt][0][0], s[qt][t4]);
        s[qt][t4] = mfma16(kh1, qf[qt][1][0], s[qt][t4]);
        s[qt][t4] = mfma16(kh1, qf[qt][1][1], s[qt][t4]);
        s[qt][t4] = mfma16(kl1, qf[qt][1][0], s[qt][t4]);
      }
      __builtin_amdgcn_s_setprio(0);
    }

    // ---- online softmax (defer-max THR=8, log2 domain) + P (f16) -> lp ----
    #pragma unroll
    for (int qt = 0; qt < 4; ++qt) {
      float cm = -__builtin_inff();
      #pragma unroll
      for (int t4 = 0; t4 < 4; ++t4)
        #pragma unroll
        for (int r = 0; r < 4; ++r) cm = fmaxf(cm, s[qt][t4][r]);
      cm = fmaxf(cm, __shfl_xor(cm, 16));
      cm = fmaxf(cm, __shfl_xor(cm, 32));
      if (__any(cm > m[qt] + 8.0f)) {
        float mnew = fmaxf(m[qt], cm);
        float sc = exp2f(m[qt] - mnew);
        m[qt] = mnew;
        l[qt] *= sc;
        #pragma unroll
        for (int cht = 0; cht < 4; ++cht) O[qt][cht] *= sc;
      }
      float ps = 0.f;
      int rowb = (qt * 16 + lq) * 64;
      #pragma unroll
      for (int t4 = 0; t4 < 4; ++t4) {
        float p0 = exp2f(s[qt][t4][0] - m[qt]);
        float p1 = exp2f(s[qt][t4][1] - m[qt]);
        float p2 = exp2f(s[qt][t4][2] - m[qt]);
        float p3 = exp2f(s[qt][t4][3] - m[qt]);
        ps += (p0 + p1) + (p2 + p3);
        f16x4 ph;
        ph[0] = (_Float16)p0;
        ph[1] = (_Float16)p1;
        ph[2] = (_Float16)p2;
        ph[3] = (_Float16)p3;
        int col = (t4 * 16 + g * 4) ^ ((lq & 7) << 3);
        *(f16x4*)&lp[wv][rowb + col] = ph;
      }
      ps += __shfl_xor(ps, 16);
      ps += __shfl_xor(ps, 32);
      l[qt] += ps;
    }

    // ---- PV: O^T += V^T-frag x P^T-frag, 2-term f16, V direct from global ----
    #pragma unroll
    for (int ks = 0; ks < 2; ++ks) {
      int kg = kbase + ks * 32 + g * 8;
      int kr = rowdiv(kg, w), kc = kg - kr * w;
      size_t vpo = (size_t)b * 64 * 16384 + (size_t)((sx + kr) * 128 + sy + kc);
      f16x8 vfh[4], vfl[4];
      #pragma unroll
      for (int cht = 0; cht < 4; ++cht) {
        size_t a = vpo + (size_t)(cht * 16 + lq) * 16384;
        vfh[cht] = *(const f16x8*)(Vh + a);
        vfl[cht] = *(const f16x8*)(Vl + a);
      }
      int pcol = (ks * 32 + g * 8) ^ ((lq & 7) << 3);
      #pragma unroll
      for (int qt = 0; qt < 4; ++qt) {
        int rowb = (qt * 16 + lq) * 64;
        f16x8 pb = *(f16x8*)&lp[wv][rowb + pcol];
        __builtin_amdgcn_s_setprio(1);
        #pragma unroll
        for (int cht = 0; cht < 4; ++cht) {
          O[qt][cht] = mfma16h(vfh[cht], pb, O[qt][cht]);
          O[qt][cht] = mfma16h(vfl[cht], pb, O[qt][cht]);
        }
        __builtin_amdgcn_s_setprio(0);
      }
    }
  }

  // epilogue: out = O/l + residual
  #pragma unroll
  for (int qt = 0; qt < 4; ++qt) {
    float inv = 1.0f / l[qt];
    int qpix = (r0 + (qt >> 1)) * 128 + sy + (qt & 1) * 16 + lq;
    #pragma unroll
    for (int cht = 0; cht < 4; ++cht)
      #pragma unroll
      for (int r = 0; r < 4; ++r) {
        int chn = cht * 16 + g * 4 + r;
        size_t idx = ((size_t)b * 64 + chn) * 16384 + qpix;
        OUT[idx] = O[qt][cht][r] * inv + RES[idx];
      }
  }
}

extern "C" void kernel_launch(void* const* d_in, const int* in_sizes, int n_in,
                              void* d_out, int out_size, void* d_ws, size_t ws_size,
                              hipStream_t stream) {
  const float* x   = (const float*)d_in[0];
  const float* Wq1 = (const float*)d_in[1];
  const float* Wk1 = (const float*)d_in[2];
  const float* Wv1 = (const float*)d_in[3];
  const float* Wq2 = (const float*)d_in[4];
  const float* Wk2 = (const float*)d_in[5];
  const float* Wv2 = (const float*)d_in[6];
  const float* bq1 = (const float*)d_in[7];
  /* bk1 = d_in[8], bk2 = d_in[11]: exactly cancel under softmax */
  const float* bv1 = (const float*)d_in[9];
  const float* bq2 = (const float*)d_in[10];
  const float* bv2 = (const float*)d_in[12];
  float* out = (float*)d_out;

  const size_t IMG = (size_t)8 * 16384;
  __bf16* QT = (__bf16*)d_ws;               // [8][16384][128]
  __bf16* KT = QT + IMG * 128;              // [8][16384][128]
  _Float16* Vh = (_Float16*)(KT + IMG * 128); // [8][64][16384]
  _Float16* Vl = Vh + IMG * 64;             // [8][64][16384]

  dim3 pgrid(64, 8);
  // layer 1
  proj_kernel<<<pgrid, 256, 0, stream>>>(x, Wq1, Wk1, Wv1, bq1, bv1, QT, KT, Vh, Vl);
  attn_kernel<<<512, 256, 0, stream>>>(QT, KT, Vh, Vl, x, out);
  // layer 2 (reads layer-1 output from d_out; residual aliases output safely)
  proj_kernel<<<pgrid, 256, 0, stream>>>(out, Wq2, Wk2, Wv2, bq2, bv2, QT, KT, Vh, Vl);
  attn_kernel<<<512, 256, 0, stream>>>(QT, KT, Vh, Vl, out, out);
}

// Round 17
// 577.027 us; speedup vs baseline: 1.4344x; 1.1821x over previous
//
#include <hip/hip_runtime.h>
#include <hip/hip_bf16.h>

typedef __attribute__((ext_vector_type(8))) __bf16 bf16x8;
typedef __attribute__((ext_vector_type(4))) __bf16 bf16x4;
typedef __attribute__((ext_vector_type(8))) _Float16 f16x8;
typedef __attribute__((ext_vector_type(4))) _Float16 f16x4;
typedef __attribute__((ext_vector_type(4))) float f32x4;

#define LOG2E 1.44269504088896340736f

__device__ inline f32x4 mfma16(bf16x8 a, bf16x8 b, f32x4 c) {
  return __builtin_amdgcn_mfma_f32_16x16x32_bf16(a, b, c, 0, 0, 0);
}
__device__ inline f32x4 mfma16h(f16x8 a, f16x8 b, f32x4 c) {
  return __builtin_amdgcn_mfma_f32_16x16x32_f16(a, b, c, 0, 0, 0);
}

// row/w division for w in {32,48}, kg < 4096
__device__ inline int rowdiv(int kg, int w) {
  return (w == 32) ? (kg >> 5) : ((kg * 43691) >> 21);
}

// ------------------------------------------------------------------
// Projection (bf16-pair 3-term GEMM internally, unchanged).
// Outputs: QT f16-pair [B][16384][qh64|ql64], KT f16 single [B][16384][64],
// Vh/Vl f16-pair [B][64][16384] ch-major.
// Q scaled by log2(e); bk dropped (softmax-invariant).
// QK precision plan: s = kh*(qh+ql) -- K single f16 (11-bit), Q f16-pair
// (22-bit); dropped kl*q term sigma ~ 2^-12 * sigma_s ~ 0.006 log2 units.
// ------------------------------------------------------------------
__global__ __launch_bounds__(256) void proj_kernel(
    const float* __restrict__ X, const float* __restrict__ Wq,
    const float* __restrict__ Wk, const float* __restrict__ Wv,
    const float* __restrict__ bq, const float* __restrict__ bv,
    _Float16* __restrict__ QT, _Float16* __restrict__ KT,
    _Float16* __restrict__ Vh, _Float16* __restrict__ Vl)
{
  const int b = blockIdx.y;
  const int pixbase = blockIdx.x * 256;
  const int t = threadIdx.x;
  __shared__ __align__(16) __bf16 xs[256 * 128]; // [pix][hi64|lo64], row-XOR-swizzled

  { // stage X tile split into hi/lo
    const float* xp = X + (size_t)b * 64 * 16384 + pixbase + t;
    #pragma unroll
    for (int c8 = 0; c8 < 8; ++c8) {
      bf16x8 vh, vl;
      #pragma unroll
      for (int i = 0; i < 8; ++i) {
        float x = xp[(size_t)(c8 * 8 + i) * 16384];
        __bf16 h = (__bf16)x;
        vh[i] = h;
        vl[i] = (__bf16)(x - (float)h);
      }
      int col = (c8 * 8) ^ ((t & 7) << 3);
      *(bf16x8*)&xs[t * 128 + col] = vh;
      *(bf16x8*)&xs[t * 128 + 64 + col] = vl;
    }
  }
  __syncthreads();

  const int wv = t >> 6, lane = t & 63, g = lane >> 4, lq = lane & 15;

  // X as B-fragments: B[k=ci][n=pix], hi and lo
  bf16x8 xf[4][2][2];
  #pragma unroll
  for (int nt = 0; nt < 4; ++nt)
    #pragma unroll
    for (int ks = 0; ks < 2; ++ks) {
      int pixl = wv * 64 + nt * 16 + lq;
      int col = (ks * 32 + g * 8) ^ ((pixl & 7) << 3);
      xf[nt][ks][0] = *(bf16x8*)&xs[pixl * 128 + col];
      xf[nt][ks][1] = *(bf16x8*)&xs[pixl * 128 + 64 + col];
    }

  #pragma unroll
  for (int mat = 0; mat < 3; ++mat) {
    const float* Wm = (mat == 0) ? Wq : (mat == 1) ? Wk : Wv;
    #pragma unroll
    for (int mt = 0; mt < 4; ++mt) {
      // W as A-fragments: A[m=co][k=ci], co = mt*16 + lq, hi/lo split
      bf16x8 wh[2], wl[2];
      #pragma unroll
      for (int ks = 0; ks < 2; ++ks) {
        const float* wp = Wm + (mt * 16 + lq) * 64 + ks * 32 + g * 8;
        f32x4 w0 = *(const f32x4*)wp;
        f32x4 w1 = *(const f32x4*)(wp + 4);
        bf16x8 fh, fl;
        #pragma unroll
        for (int r = 0; r < 4; ++r) {
          __bf16 h0 = (__bf16)w0[r]; fh[r] = h0; fl[r] = (__bf16)(w0[r] - (float)h0);
          __bf16 h1 = (__bf16)w1[r]; fh[4 + r] = h1; fl[4 + r] = (__bf16)(w1[r] - (float)h1);
        }
        wh[ks] = fh; wl[ks] = fl;
      }
      f32x4 binit = {0.f, 0.f, 0.f, 0.f};
      if (mat == 0) binit = *(const f32x4*)(bq + mt * 16 + g * 4);
      if (mat == 2) binit = *(const f32x4*)(bv + mt * 16 + g * 4);
      f32x4 acc[4];
      #pragma unroll
      for (int nt = 0; nt < 4; ++nt) acc[nt] = binit;
      #pragma unroll
      for (int nt = 0; nt < 4; ++nt)
        #pragma unroll
        for (int ks = 0; ks < 2; ++ks) {
          acc[nt] = mfma16(wh[ks], xf[nt][ks][0], acc[nt]);
          acc[nt] = mfma16(wh[ks], xf[nt][ks][1], acc[nt]);
          acc[nt] = mfma16(wl[ks], xf[nt][ks][0], acc[nt]);
        }
      // D layout: m = co = mt*16 + g*4 + r ; n = pix = nt*16 + lq
      #pragma unroll
      for (int nt = 0; nt < 4; ++nt) {
        int pix = pixbase + wv * 64 + nt * 16 + lq;
        if (mat == 2) {
          #pragma unroll
          for (int r = 0; r < 4; ++r) {
            float v = acc[nt][r];
            _Float16 h = (_Float16)v;
            size_t idx = ((size_t)b * 64 + mt * 16 + g * 4 + r) * 16384 + pix;
            Vh[idx] = h;
            Vl[idx] = (_Float16)(v - (float)h);
          }
        } else if (mat == 0) {
          f16x4 oh, ol;
          #pragma unroll
          for (int r = 0; r < 4; ++r) {
            float v = acc[nt][r] * LOG2E;
            _Float16 h = (_Float16)v;
            oh[r] = h;
            ol[r] = (_Float16)(v - (float)h);
          }
          _Float16* dst = QT + ((size_t)b * 16384 + pix) * 128 + mt * 16 + g * 4;
          *(f16x4*)dst = oh;
          *(f16x4*)(dst + 64) = ol;
        } else {
          f16x4 oh;
          #pragma unroll
          for (int r = 0; r < 4; ++r) oh[r] = (_Float16)acc[nt][r];
          *(f16x4*)(KT + ((size_t)b * 16384 + pix) * 64 + mt * 16 + g * 4) = oh;
        }
      }
    }
  }
}

// ------------------------------------------------------------------
// Flash attention, barrier-free. 4 waves x 64 queries (2 rows) per block;
// K/V fragments direct from global, LDS only for the per-wave P plane.
// QK^T: 2-term f16 (K single-plane -- HALVES K fetch + QK MFMAs 96->64).
// PV: 2-term f16 (R16-proven). Defer-max THR=8 (log2 domain) bounds
// p <= 2^8.3, f16-safe.
// Block decode: xcd = batch (i&7), windows desc-Nk.
// ------------------------------------------------------------------
__global__ __launch_bounds__(256, 2) void attn_kernel(
    const _Float16* __restrict__ QT, const _Float16* __restrict__ KT,
    const _Float16* __restrict__ Vh, const _Float16* __restrict__ Vl,
    const float* RES, float* OUT)
{
  const int i = blockIdx.x;
  const int b = i & 7;
  const int s_lin = i >> 3;
  const int wo = s_lin >> 2;
  const int qb = s_lin & 3;
  int win;
  {
    int w3 = (wo * 11) >> 5; // wo/3 for wo<9
    win = (wo < 9) ? (wo + w3) : ((wo < 12) ? (3 + ((wo - 9) << 2)) : wo);
  }
  const int wi = win >> 2, wj = win & 3;
  const int sx = wi * 32, sy = wj * 32;
  const int w = (128 - sy) < 48 ? (128 - sy) : 48;
  const int h = (128 - sx) < 48 ? (128 - sx) : 48;
  const int Nk = h * w, nch = Nk >> 6;
  const int t = threadIdx.x;
  const int wv = t >> 6, lane = t & 63, g = lane >> 4, lq = lane & 15;

  __shared__ __align__(16) _Float16 lp[4][64 * 64]; // per-wave P (f16, 32 KB)

  // Q fragments (B of S^T): B[k=ch][n=q]; wave owns rows r0,r0+1
  const int r0 = sx + qb * 8 + wv * 2;
  f16x8 qf[4][2][2]; // [qt][ks][hi/lo]
  #pragma unroll
  for (int qt = 0; qt < 4; ++qt) {
    int qpix = (r0 + (qt >> 1)) * 128 + sy + (qt & 1) * 16 + lq;
    const _Float16* qp = QT + ((size_t)b * 16384 + qpix) * 128;
    qf[qt][0][0] = *(const f16x8*)(qp + g * 8);
    qf[qt][1][0] = *(const f16x8*)(qp + 32 + g * 8);
    qf[qt][0][1] = *(const f16x8*)(qp + 64 + g * 8);
    qf[qt][1][1] = *(const f16x8*)(qp + 96 + g * 8);
  }

  f32x4 O[4][4]; // O^T acc: m = ch = cht*16 + g*4 + r ; n = q
  #pragma unroll
  for (int qt = 0; qt < 4; ++qt)
    #pragma unroll
    for (int cht = 0; cht < 4; ++cht) O[qt][cht] = (f32x4){0.f, 0.f, 0.f, 0.f};
  float m[4] = {-__builtin_inff(), -__builtin_inff(), -__builtin_inff(), -__builtin_inff()};
  float l[4] = {0.f, 0.f, 0.f, 0.f};

  for (int ch = 0; ch < nch; ++ch) {
    const int kbase = ch * 64;

    // ---- QK^T: S^T[key][q], K (single f16 plane) direct from global ----
    f32x4 s[4][4]; // [qt][t4]
    #pragma unroll
    for (int qt = 0; qt < 4; ++qt)
      #pragma unroll
      for (int t4 = 0; t4 < 4; ++t4) s[qt][t4] = (f32x4){0.f, 0.f, 0.f, 0.f};
    #pragma unroll
    for (int t4 = 0; t4 < 4; ++t4) {
      int kg = kbase + t4 * 16 + lq;
      int kr = rowdiv(kg, w), kc = kg - kr * w;
      const _Float16* kp = KT + ((size_t)b * 16384 + (sx + kr) * 128 + sy + kc) * 64 + g * 8;
      f16x8 kh0 = *(const f16x8*)(kp);
      f16x8 kh1 = *(const f16x8*)(kp + 32);
      __builtin_amdgcn_s_setprio(1);
      #pragma unroll
      for (int qt = 0; qt < 4; ++qt) {
        s[qt][t4] = mfma16h(kh0, qf[qt][0][0], s[qt][t4]);
        s[qt][t4] = mfma16h(kh0, qf[qt][0][1], s[qt][t4]);
        s[qt][t4] = mfma16h(kh1, qf[qt][1][0], s[qt][t4]);
        s[qt][t4] = mfma16h(kh1, qf[qt][1][1], s[qt][t4]);
      }
      __builtin_amdgcn_s_setprio(0);
    }

    // ---- online softmax (defer-max THR=8, log2 domain) + P (f16) -> lp ----
    #pragma unroll
    for (int qt = 0; qt < 4; ++qt) {
      float cm = -__builtin_inff();
      #pragma unroll
      for (int t4 = 0; t4 < 4; ++t4)
        #pragma unroll
        for (int r = 0; r < 4; ++r) cm = fmaxf(cm, s[qt][t4][r]);
      cm = fmaxf(cm, __shfl_xor(cm, 16));
      cm = fmaxf(cm, __shfl_xor(cm, 32));
      if (__any(cm > m[qt] + 8.0f)) {
        float mnew = fmaxf(m[qt], cm);
        float sc = exp2f(m[qt] - mnew);
        m[qt] = mnew;
        l[qt] *= sc;
        #pragma unroll
        for (int cht = 0; cht < 4; ++cht) O[qt][cht] *= sc;
      }
      float ps = 0.f;
      int rowb = (qt * 16 + lq) * 64;
      #pragma unroll
      for (int t4 = 0; t4 < 4; ++t4) {
        float p0 = exp2f(s[qt][t4][0] - m[qt]);
        float p1 = exp2f(s[qt][t4][1] - m[qt]);
        float p2 = exp2f(s[qt][t4][2] - m[qt]);
        float p3 = exp2f(s[qt][t4][3] - m[qt]);
        ps += (p0 + p1) + (p2 + p3);
        f16x4 ph;
        ph[0] = (_Float16)p0;
        ph[1] = (_Float16)p1;
        ph[2] = (_Float16)p2;
        ph[3] = (_Float16)p3;
        int col = (t4 * 16 + g * 4) ^ ((lq & 7) << 3);
        *(f16x4*)&lp[wv][rowb + col] = ph;
      }
      ps += __shfl_xor(ps, 16);
      ps += __shfl_xor(ps, 32);
      l[qt] += ps;
    }

    // ---- PV: O^T += V^T-frag x P^T-frag, 2-term f16, V direct from global ----
    #pragma unroll
    for (int ks = 0; ks < 2; ++ks) {
      int kg = kbase + ks * 32 + g * 8;
      int kr = rowdiv(kg, w), kc = kg - kr * w;
      size_t vpo = (size_t)b * 64 * 16384 + (size_t)((sx + kr) * 128 + sy + kc);
      f16x8 vfh[4], vfl[4];
      #pragma unroll
      for (int cht = 0; cht < 4; ++cht) {
        size_t a = vpo + (size_t)(cht * 16 + lq) * 16384;
        vfh[cht] = *(const f16x8*)(Vh + a);
        vfl[cht] = *(const f16x8*)(Vl + a);
      }
      int pcol = (ks * 32 + g * 8) ^ ((lq & 7) << 3);
      #pragma unroll
      for (int qt = 0; qt < 4; ++qt) {
        int rowb = (qt * 16 + lq) * 64;
        f16x8 pb = *(f16x8*)&lp[wv][rowb + pcol];
        __builtin_amdgcn_s_setprio(1);
        #pragma unroll
        for (int cht = 0; cht < 4; ++cht) {
          O[qt][cht] = mfma16h(vfh[cht], pb, O[qt][cht]);
          O[qt][cht] = mfma16h(vfl[cht], pb, O[qt][cht]);
        }
        __builtin_amdgcn_s_setprio(0);
      }
    }
  }

  // epilogue: out = O/l + residual
  #pragma unroll
  for (int qt = 0; qt < 4; ++qt) {
    float inv = 1.0f / l[qt];
    int qpix = (r0 + (qt >> 1)) * 128 + sy + (qt & 1) * 16 + lq;
    #pragma unroll
    for (int cht = 0; cht < 4; ++cht)
      #pragma unroll
      for (int r = 0; r < 4; ++r) {
        int chn = cht * 16 + g * 4 + r;
        size_t idx = ((size_t)b * 64 + chn) * 16384 + qpix;
        OUT[idx] = O[qt][cht][r] * inv + RES[idx];
      }
  }
}

extern "C" void kernel_launch(void* const* d_in, const int* in_sizes, int n_in,
                              void* d_out, int out_size, void* d_ws, size_t ws_size,
                              hipStream_t stream) {
  const float* x   = (const float*)d_in[0];
  const float* Wq1 = (const float*)d_in[1];
  const float* Wk1 = (const float*)d_in[2];
  const float* Wv1 = (const float*)d_in[3];
  const float* Wq2 = (const float*)d_in[4];
  const float* Wk2 = (const float*)d_in[5];
  const float* Wv2 = (const float*)d_in[6];
  const float* bq1 = (const float*)d_in[7];
  /* bk1 = d_in[8], bk2 = d_in[11]: exactly cancel under softmax */
  const float* bv1 = (const float*)d_in[9];
  const float* bq2 = (const float*)d_in[10];
  const float* bv2 = (const float*)d_in[12];
  float* out = (float*)d_out;

  const size_t IMG = (size_t)8 * 16384;
  _Float16* QT = (_Float16*)d_ws;   // [8][16384][128] (qh|ql)
  _Float16* KT = QT + IMG * 128;    // [8][16384][64]  (kh only)
  _Float16* Vh = KT + IMG * 64;     // [8][64][16384]
  _Float16* Vl = Vh + IMG * 64;     // [8][64][16384]

  dim3 pgrid(64, 8);
  // layer 1
  proj_kernel<<<pgrid, 256, 0, stream>>>(x, Wq1, Wk1, Wv1, bq1, bv1, QT, KT, Vh, Vl);
  attn_kernel<<<512, 256, 0, stream>>>(QT, KT, Vh, Vl, x, out);
  // layer 2 (reads layer-1 output from d_out; residual aliases output safely)
  proj_kernel<<<pgrid, 256, 0, stream>>>(out, Wq2, Wk2, Wv2, bq2, bv2, QT, KT, Vh, Vl);
  attn_kernel<<<512, 256, 0, stream>>>(QT, KT, Vh, Vl, out, out);
}